// Round 6
// baseline (345.937 us; speedup 1.0000x reference)
//
#include <hip/hip_runtime.h>
#include <hip/hip_bf16.h>
#include <cstdint>

// ---------------------------------------------------------------------------
// GCFAgg, algebraically reduced (B=8, N=4096, D=512, fp32 in/out):
//   C[b] = x[b]^T x[b]  (512x512), u[b] = colsum(x[b])
//   G[b] = W2 C WR^T + (W2u)bR^T + b2(WRu)^T + N b2 bR^T     (512x512)
//   out[b] = x[b] (W1^T G[b]) + 1 (b1^T G[b])
// All big GEMMs in bf16 hi/lo 3-pass MFMA (A*B ~= Ah*Bh + Ah*Bl + Al*Bh),
// rel err ~1e-5 per GEMM vs fp32 (end-to-end ~1e-4 vs out sigma~280).
// Dispatches (7): memset(C,u) -> splitx+w1t -> xtx+vecs -> s1 -> s2
//                 -> s3+v2 -> d
// Workspace 85 MB: G-pair aliases dead C, H-pair aliases dead T.
// ---------------------------------------------------------------------------

typedef __attribute__((ext_vector_type(4))) float f32x4;
typedef __attribute__((ext_vector_type(4))) float fl4;
typedef __attribute__((ext_vector_type(8))) short s16x8;
typedef __attribute__((ext_vector_type(4))) short s16x4;

#define MFMA16(a, b, c) __builtin_amdgcn_mfma_f32_16x16x32_bf16((a), (b), (c), 0, 0, 0)

static __device__ __forceinline__ short f2bf(float f) {
    __hip_bfloat16 h = __float2bfloat16(f);
    return *reinterpret_cast<short*>(&h);
}
static __device__ __forceinline__ float bf2f(short s) {
    __hip_bfloat16 h = *reinterpret_cast<__hip_bfloat16*>(&s);
    return __bfloat162float(h);
}
// By-value hi/lo split (ext_vector elements can't bind to references).
struct HL { short h, l; };
static __device__ __forceinline__ HL split2(float v) {
    HL r;
    r.h = f2bf(v);
    r.l = f2bf(v - bf2f(r.h));
    return r;
}
// XOR swizzle at 8-element (16B) granularity within 64-elem rows: rows 0..7 of
// each stripe land on disjoint 16B slots -> wave64 ds_read_b128 is 2-way max
// (free, m136). Involution; bits 0..2 of col untouched so 4-elem-granular
// writes stay consistent with 8-elem-granular reads.
static __device__ __forceinline__ int swz(int row, int col) {
    return col ^ ((row & 7) << 3);
}

// ---------------------------------------------------------------------------
// Shared 128x128-tile MFMA machinery (4 waves in 2x2, 64x64 each).
// A-frag: A[row=wr*64+fr*16+(l&15)][k=kk*32+(l>>4)*8+j]; B-frag same w/ wc/fc.
// C-frag: within 16x16, row=(l>>4)*4+j, col=l&15. acc = A . B^T (k contract).
// ---------------------------------------------------------------------------
__device__ __forceinline__ void mm128_compute(short* sAh, short* sAl,
                                              short* sBh, short* sBl,
                                              f32x4 acc[4][4]) {
    int lane = threadIdx.x & 63, wid = threadIdx.x >> 6;
    int wr = wid >> 1, wc = wid & 1;
    int l15 = lane & 15, l4 = lane >> 4;
#pragma unroll
    for (int kk = 0; kk < 2; ++kk) {
        s16x8 af[4], alf[4];
#pragma unroll
        for (int fr = 0; fr < 4; ++fr) {
            int row = wr * 64 + fr * 16 + l15;
            int k = kk * 32 + (l4 << 3);
            int di = row * 64 + swz(row, k);
            af[fr] = *reinterpret_cast<s16x8*>(&sAh[di]);
            alf[fr] = *reinterpret_cast<s16x8*>(&sAl[di]);
        }
#pragma unroll
        for (int fc = 0; fc < 4; ++fc) {
            int row = wc * 64 + fc * 16 + l15;
            int k = kk * 32 + (l4 << 3);
            int di = row * 64 + swz(row, k);
            s16x8 bh = *reinterpret_cast<s16x8*>(&sBh[di]);
            s16x8 bl = *reinterpret_cast<s16x8*>(&sBl[di]);
#pragma unroll
            for (int fr = 0; fr < 4; ++fr) {
                acc[fr][fc] = MFMA16(af[fr], bh, acc[fr][fc]);
                acc[fr][fc] = MFMA16(af[fr], bl, acc[fr][fc]);
                acc[fr][fc] = MFMA16(alf[fr], bh, acc[fr][fc]);
            }
        }
    }
}

// Both operands pre-split bf16, [128 rows][ld], K consumed in 64-chunks.
__device__ __forceinline__ void mm128_presplit(
    const short* __restrict__ Ah, const short* __restrict__ Al, int lda,
    const short* __restrict__ Bh, const short* __restrict__ Bl, int ldb,
    int nk, short* sAh, short* sAl, short* sBh, short* sBl, f32x4 acc[4][4]) {
    int tid = threadIdx.x;
    for (int kt = 0; kt < nk; ++kt) {
        __syncthreads();
        int k0 = kt * 64;
#pragma unroll
        for (int i = 0; i < 4; ++i) {
            int chunk = i * 256 + tid;          // 1024 16B-chunks per array
            int row = chunk >> 3;
            int cs = (chunk & 7) << 3;
            int di = row * 64 + swz(row, cs);
            *reinterpret_cast<s16x8*>(&sAh[di]) =
                *reinterpret_cast<const s16x8*>(&Ah[(size_t)row * lda + k0 + cs]);
            *reinterpret_cast<s16x8*>(&sAl[di]) =
                *reinterpret_cast<const s16x8*>(&Al[(size_t)row * lda + k0 + cs]);
            *reinterpret_cast<s16x8*>(&sBh[di]) =
                *reinterpret_cast<const s16x8*>(&Bh[(size_t)row * ldb + k0 + cs]);
            *reinterpret_cast<s16x8*>(&sBl[di]) =
                *reinterpret_cast<const s16x8*>(&Bl[(size_t)row * ldb + k0 + cs]);
        }
        __syncthreads();
        mm128_compute(sAh, sAl, sBh, sBl, acc);
    }
}

// Both operands fp32, split to hi/lo on the fly during staging.
__device__ __forceinline__ void mm128_split32(
    const float* __restrict__ A32, int lda,
    const float* __restrict__ B32, int ldb,
    int nk, short* sAh, short* sAl, short* sBh, short* sBl, f32x4 acc[4][4]) {
    int tid = threadIdx.x;
    for (int kt = 0; kt < nk; ++kt) {
        __syncthreads();
        int k0 = kt * 64;
#pragma unroll
        for (int i = 0; i < 8; ++i) {
            int chunk = i * 256 + tid;          // 2048 float4-chunks per array
            int row = chunk >> 4;
            int c4 = (chunk & 15) << 2;
            int di = row * 64 + swz(row, c4);
            fl4 va = *reinterpret_cast<const fl4*>(&A32[(size_t)row * lda + k0 + c4]);
            fl4 vb = *reinterpret_cast<const fl4*>(&B32[(size_t)row * ldb + k0 + c4]);
            s16x4 ah, al, bh, bl;
#pragma unroll
            for (int j = 0; j < 4; ++j) {
                HL pa = split2(va[j]); ah[j] = pa.h; al[j] = pa.l;
                HL pb = split2(vb[j]); bh[j] = pb.h; bl[j] = pb.l;
            }
            *reinterpret_cast<s16x4*>(&sAh[di]) = ah;
            *reinterpret_cast<s16x4*>(&sAl[di]) = al;
            *reinterpret_cast<s16x4*>(&sBh[di]) = bh;
            *reinterpret_cast<s16x4*>(&sBl[di]) = bl;
        }
        __syncthreads();
        mm128_compute(sAh, sAl, sBh, sBl, acc);
    }
}

// A fp32 (split on the fly), B pre-split bf16.
__device__ __forceinline__ void mm128_mixA32(
    const float* __restrict__ A32, int lda,
    const short* __restrict__ Bh, const short* __restrict__ Bl, int ldb,
    int nk, short* sAh, short* sAl, short* sBh, short* sBl, f32x4 acc[4][4]) {
    int tid = threadIdx.x;
    for (int kt = 0; kt < nk; ++kt) {
        __syncthreads();
        int k0 = kt * 64;
#pragma unroll
        for (int i = 0; i < 8; ++i) {
            int chunk = i * 256 + tid;
            int row = chunk >> 4;
            int c4 = (chunk & 15) << 2;
            fl4 va = *reinterpret_cast<const fl4*>(&A32[(size_t)row * lda + k0 + c4]);
            s16x4 ah, al;
#pragma unroll
            for (int j = 0; j < 4; ++j) {
                HL pa = split2(va[j]); ah[j] = pa.h; al[j] = pa.l;
            }
            int di = row * 64 + swz(row, c4);
            *reinterpret_cast<s16x4*>(&sAh[di]) = ah;
            *reinterpret_cast<s16x4*>(&sAl[di]) = al;
        }
#pragma unroll
        for (int i = 0; i < 4; ++i) {
            int chunk = i * 256 + tid;
            int row = chunk >> 3;
            int cs = (chunk & 7) << 3;
            int di = row * 64 + swz(row, cs);
            *reinterpret_cast<s16x8*>(&sBh[di]) =
                *reinterpret_cast<const s16x8*>(&Bh[(size_t)row * ldb + k0 + cs]);
            *reinterpret_cast<s16x8*>(&sBl[di]) =
                *reinterpret_cast<const s16x8*>(&Bl[(size_t)row * ldb + k0 + cs]);
        }
        __syncthreads();
        mm128_compute(sAh, sAl, sBh, sBl, acc);
    }
}

#define GEMM_LDS short sAh[128*64], sAl[128*64], sBh[128*64], sBl[128*64]

// ---------------------------------------------------------------------------
// splitx (blocks 0..4095): x -> xth/xtl [b][512][4096] + u[b][d] (atomic).
// w1t   (blocks 4096..4159): W1t[d][a] = split(W1[a][d]).
// ---------------------------------------------------------------------------
__global__ __launch_bounds__(256, 4)
void splitx_w1t_kernel(const float* __restrict__ x, short* __restrict__ xth,
                       short* __restrict__ xtl, float* __restrict__ u,
                       const float* __restrict__ W1, short* __restrict__ W1th,
                       short* __restrict__ W1tl) {
    __shared__ float lx[64 * 65];
    int bid = blockIdx.x, t = threadIdx.x;
    if (bid < 4096) {
        int nt = bid >> 3, dt = bid & 7;
        int b = nt >> 6, ntb = nt & 63;
        int d0 = dt * 64;
#pragma unroll
        for (int i = 0; i < 4; ++i) {
            int flat = i * 256 + t;             // 1024 float4s = 64x64 tile
            int r = flat >> 4, c4 = (flat & 15) << 2;
            fl4 v = *reinterpret_cast<const fl4*>(
                &x[((size_t)nt * 64 + r) * 512 + d0 + c4]);
#pragma unroll
            for (int j = 0; j < 4; ++j) lx[r * 65 + c4 + j] = v[j];
        }
        __syncthreads();
        int dl = t >> 2, nq = (t & 3) * 16;     // thread: one d, 16 n's
        float s = 0.f;
        s16x8 th[2], tl[2];
#pragma unroll
        for (int k = 0; k < 16; ++k) {
            float v = lx[(nq + k) * 65 + dl];
            s += v;
            HL p = split2(v);
            th[k >> 3][k & 7] = p.h;
            tl[k >> 3][k & 7] = p.l;
        }
        size_t ta = ((size_t)b * 512 + d0 + dl) * 4096 + (size_t)ntb * 64 + nq;
        *reinterpret_cast<s16x8*>(&xth[ta]) = th[0];
        *reinterpret_cast<s16x8*>(&xth[ta + 8]) = th[1];
        *reinterpret_cast<s16x8*>(&xtl[ta]) = tl[0];
        *reinterpret_cast<s16x8*>(&xtl[ta + 8]) = tl[1];
        s += __shfl_xor(s, 1, 64);
        s += __shfl_xor(s, 2, 64);
        if ((t & 3) == 0) atomicAdd(&u[b * 512 + d0 + dl], s);
    } else {
        int wb = bid - 4096;
        int a0 = (wb >> 3) * 64, d0 = (wb & 7) * 64;
#pragma unroll
        for (int i = 0; i < 4; ++i) {
            int flat = i * 256 + t;
            int r = flat >> 4, c4 = (flat & 15) << 2;
            fl4 v = *reinterpret_cast<const fl4*>(
                &W1[(size_t)(a0 + r) * 512 + d0 + c4]);
#pragma unroll
            for (int j = 0; j < 4; ++j) lx[r * 65 + c4 + j] = v[j];
        }
        __syncthreads();
        int dl = t >> 2, aq = (t & 3) * 16;
        s16x8 th[2], tl[2];
#pragma unroll
        for (int k = 0; k < 16; ++k) {
            HL p = split2(lx[(aq + k) * 65 + dl]);
            th[k >> 3][k & 7] = p.h;
            tl[k >> 3][k & 7] = p.l;
        }
        size_t o = (size_t)(d0 + dl) * 512 + a0 + aq;
        *reinterpret_cast<s16x8*>(&W1th[o]) = th[0];
        *reinterpret_cast<s16x8*>(&W1th[o + 8]) = th[1];
        *reinterpret_cast<s16x8*>(&W1tl[o]) = tl[0];
        *reinterpret_cast<s16x8*>(&W1tl[o + 8]) = tl[1];
    }
}

// ---------------------------------------------------------------------------
// blocks 0..63:   vecs: p2[b] = W2 u[b], y[b] = WR u[b]  (8 b x 8 a-groups)
// blocks 64..575: xtx:  C[b] += xt[d-tile] . xt[e-tile]^T over n-slice, atomic
// vecs blocks first so they retire early; xtx keeps perfect 512-block packing.
// ---------------------------------------------------------------------------
__global__ __launch_bounds__(256, 2)
void xtx_vecs_kernel(const short* __restrict__ xth, const short* __restrict__ xtl,
                     float* __restrict__ C, const float* __restrict__ W2,
                     const float* __restrict__ WR, const float* __restrict__ u,
                     float* __restrict__ p2, float* __restrict__ y) {
    __shared__ GEMM_LDS;
    int bid = blockIdx.x, t = threadIdx.x;
    if (bid < 64) {
        float* su = (float*)sAh;                // 2KB alias
        float* red = (float*)sBh;               // [2][4][64] = 2KB alias
        int b = bid >> 3, a0 = (bid & 7) * 64;
        for (int i = t; i < 512; i += 256) su[i] = u[b * 512 + i];
        __syncthreads();
        int al = t & 63, q = t >> 6;
        const float* w2r = &W2[(size_t)(a0 + al) * 512 + q * 128];
        const float* wrr = &WR[(size_t)(a0 + al) * 512 + q * 128];
        float s2 = 0.f, sr = 0.f;
        for (int d = 0; d < 128; d += 4) {
            fl4 a4 = *reinterpret_cast<const fl4*>(&w2r[d]);
            fl4 r4 = *reinterpret_cast<const fl4*>(&wrr[d]);
#pragma unroll
            for (int j = 0; j < 4; ++j) {
                s2 += a4[j] * su[q * 128 + d + j];
                sr += r4[j] * su[q * 128 + d + j];
            }
        }
        red[(0 * 4 + q) * 64 + al] = s2;
        red[(1 * 4 + q) * 64 + al] = sr;
        __syncthreads();
        if (t < 64)
            p2[b * 512 + a0 + t] = red[t] + red[64 + t] + red[128 + t] + red[192 + t];
        else if (t < 128) {
            int a = t - 64;
            y[b * 512 + a0 + a] =
                red[256 + a] + red[320 + a] + red[384 + a] + red[448 + a];
        }
        return;
    }
    int xbid = bid - 64;
    int sl = xbid >> 7, r = xbid & 127;
    int b = r >> 4, t16 = r & 15;
    int d0 = (t16 >> 2) * 128, e0 = (t16 & 3) * 128;
    f32x4 acc[4][4] = {};
    const short* Ah = xth + ((size_t)b * 512 + d0) * 4096 + sl * 1024;
    const short* Al = xtl + ((size_t)b * 512 + d0) * 4096 + sl * 1024;
    const short* Bh = xth + ((size_t)b * 512 + e0) * 4096 + sl * 1024;
    const short* Bl = xtl + ((size_t)b * 512 + e0) * 4096 + sl * 1024;
    mm128_presplit(Ah, Al, 4096, Bh, Bl, 4096, 16, sAh, sAl, sBh, sBl, acc);
    int lane = t & 63, wid = t >> 6;
    int wr = wid >> 1, wc = wid & 1, l15 = lane & 15, l4 = lane >> 4;
    float* Cb = C + (size_t)b * 262144;
#pragma unroll
    for (int fc = 0; fc < 4; ++fc) {
        int e = e0 + wc * 64 + fc * 16 + l15;
#pragma unroll
        for (int fr = 0; fr < 4; ++fr) {
            int d = d0 + wr * 64 + fr * 16 + (l4 << 2);
#pragma unroll
            for (int j = 0; j < 4; ++j)
                atomicAdd(&Cb[(size_t)(d + j) * 512 + e], acc[fr][fc][j]);
        }
    }
}

// ---------------------------------------------------------------------------
// s1: T[b][a][e] = sum_d W2[a][d] * C[b][e][d]  (C symmetric => = (W2 C)[a,e])
// ---------------------------------------------------------------------------
__global__ __launch_bounds__(256, 2)
void s1_kernel(const float* __restrict__ W2, const float* __restrict__ C,
               float* __restrict__ T) {
    __shared__ GEMM_LDS;
    int bid = blockIdx.x;
    int b = bid >> 4, t16 = bid & 15;
    int a0 = (t16 >> 2) * 128, e0 = (t16 & 3) * 128;
    f32x4 acc[4][4] = {};
    mm128_split32(W2 + (size_t)a0 * 512, 512,
                  C + (size_t)b * 262144 + (size_t)e0 * 512, 512, 8,
                  sAh, sAl, sBh, sBl, acc);
    int lane = threadIdx.x & 63, wid = threadIdx.x >> 6;
    int wr = wid >> 1, wc = wid & 1, l15 = lane & 15, l4 = lane >> 4;
#pragma unroll
    for (int fc = 0; fc < 4; ++fc) {
        int e = e0 + wc * 64 + fc * 16 + l15;
#pragma unroll
        for (int fr = 0; fr < 4; ++fr) {
            int a = a0 + wr * 64 + fr * 16 + (l4 << 2);
#pragma unroll
            for (int j = 0; j < 4; ++j)
                T[(size_t)b * 262144 + (size_t)(a + j) * 512 + e] = acc[fr][fc][j];
        }
    }
}

// ---------------------------------------------------------------------------
// s2: G[a][c] = sum_e T[a][e] WR[c][e] + p2[a]bR[c] + b2[a]y[c] + N b2[a]bR[c]
// stored transposed + bf16-split: Gth/Gtl[b][c][a]. (G overwrites dead C.)
// ---------------------------------------------------------------------------
__global__ __launch_bounds__(256, 2)
void s2_kernel(const float* __restrict__ T, const float* __restrict__ WR,
               const float* __restrict__ bR, const float* __restrict__ b2,
               const float* __restrict__ p2, const float* __restrict__ y,
               short* __restrict__ Gth, short* __restrict__ Gtl) {
    __shared__ GEMM_LDS;
    int bid = blockIdx.x;
    int b = bid >> 4, t16 = bid & 15;
    int a0 = (t16 >> 2) * 128, c0 = (t16 & 3) * 128;
    f32x4 acc[4][4] = {};
    mm128_split32(T + (size_t)b * 262144 + (size_t)a0 * 512, 512,
                  WR + (size_t)c0 * 512, 512, 8, sAh, sAl, sBh, sBl, acc);
    int lane = threadIdx.x & 63, wid = threadIdx.x >> 6;
    int wr = wid >> 1, wc = wid & 1, l15 = lane & 15, l4 = lane >> 4;
#pragma unroll
    for (int fc = 0; fc < 4; ++fc) {
        int c = c0 + wc * 64 + fc * 16 + l15;
        float bRc = bR[c], yc = y[b * 512 + c];
#pragma unroll
        for (int fr = 0; fr < 4; ++fr) {
            int abase = a0 + wr * 64 + fr * 16 + (l4 << 2);
            s16x4 h4, l4v;
#pragma unroll
            for (int j = 0; j < 4; ++j) {
                int a = abase + j;
                float val = acc[fr][fc][j]
                          + bRc * (p2[b * 512 + a] + 4096.0f * b2[a])
                          + yc * b2[a];
                HL p = split2(val);
                h4[j] = p.h;
                l4v[j] = p.l;
            }
            size_t o = ((size_t)b * 512 + c) * 512 + abase;
            *reinterpret_cast<s16x4*>(&Gth[o]) = h4;
            *reinterpret_cast<s16x4*>(&Gtl[o]) = l4v;
        }
    }
}

// ---------------------------------------------------------------------------
// blocks 0..127:  s3: Ht[b][c][d] = sum_a W1t[d][a] Gt[b][c][a] = (W1^T G)[d,c]
// blocks 128..135: v2: v[b][c] = sum_a b1[a] * Gt[b][c][a]
// (H-pair overwrites dead T; both paths only read G.)
// ---------------------------------------------------------------------------
__global__ __launch_bounds__(256, 2)
void s3_v2_kernel(const short* __restrict__ W1th, const short* __restrict__ W1tl,
                  const short* __restrict__ Gth, const short* __restrict__ Gtl,
                  short* __restrict__ Hth, short* __restrict__ Htl,
                  const float* __restrict__ b1, float* __restrict__ v) {
    __shared__ GEMM_LDS;
    int bid = blockIdx.x, t = threadIdx.x;
    if (bid >= 128) {
        float* sb1 = (float*)sAh;               // 2KB alias
        int b = bid - 128;
        for (int i = t; i < 512; i += 256) sb1[i] = b1[i];
        __syncthreads();
        for (int c = t; c < 512; c += 256) {
            float accv = 0.f;
            size_t base = ((size_t)b * 512 + c) * 512;
            for (int a8 = 0; a8 < 512; a8 += 8) {
                s16x8 h = *reinterpret_cast<const s16x8*>(&Gth[base + a8]);
                s16x8 l = *reinterpret_cast<const s16x8*>(&Gtl[base + a8]);
#pragma unroll
                for (int j = 0; j < 8; ++j)
                    accv += (bf2f(h[j]) + bf2f(l[j])) * sb1[a8 + j];
            }
            v[b * 512 + c] = accv;
        }
        return;
    }
    int b = bid >> 4, t16 = bid & 15;
    int d0 = (t16 >> 2) * 128, c0 = (t16 & 3) * 128;
    f32x4 acc[4][4] = {};
    mm128_presplit(W1th + (size_t)d0 * 512, W1tl + (size_t)d0 * 512, 512,
                   Gth + (size_t)b * 262144 + (size_t)c0 * 512,
                   Gtl + (size_t)b * 262144 + (size_t)c0 * 512, 512, 8,
                   sAh, sAl, sBh, sBl, acc);
    int lane = t & 63, wid = t >> 6;
    int wr = wid >> 1, wc = wid & 1, l15 = lane & 15, l4 = lane >> 4;
#pragma unroll
    for (int fc = 0; fc < 4; ++fc) {
        int c = c0 + wc * 64 + fc * 16 + l15;
#pragma unroll
        for (int fr = 0; fr < 4; ++fr) {
            int dbase = d0 + wr * 64 + fr * 16 + (l4 << 2);
            s16x4 h4, l4v;
#pragma unroll
            for (int j = 0; j < 4; ++j) {
                HL p = split2(acc[fr][fc][j]);
                h4[j] = p.h;
                l4v[j] = p.l;
            }
            size_t o = ((size_t)b * 512 + c) * 512 + dbase;
            *reinterpret_cast<s16x4*>(&Hth[o]) = h4;
            *reinterpret_cast<s16x4*>(&Htl[o]) = l4v;
        }
    }
}

// ---------------------------------------------------------------------------
// d: out[n][c] = sum_d x[n][d] Ht[b][c][d] + v[b][c]. 1024 blocks; XCD
// swizzle maps batch k -> XCD k so Ht[b] (1MB pair) stays L2-resident.
// A staged from fp32 x (split on the fly), B pre-split.
// ---------------------------------------------------------------------------
__global__ __launch_bounds__(256, 2)
void d_kernel(const float* __restrict__ x,
              const short* __restrict__ Hth, const short* __restrict__ Htl,
              const float* __restrict__ v, float* __restrict__ out) {
    __shared__ GEMM_LDS;
    int bid = blockIdx.x;
    int wk = (bid & 7) * 128 + (bid >> 3);      // bijective, batch<->XCD
    int mt = wk >> 2, ct = wk & 3;
    int m0 = mt * 128, c0 = ct * 128;
    int b = m0 >> 12;
    f32x4 acc[4][4] = {};
    mm128_mixA32(x + (size_t)m0 * 512, 512,
                 Hth + (size_t)b * 262144 + (size_t)c0 * 512,
                 Htl + (size_t)b * 262144 + (size_t)c0 * 512, 512, 8,
                 sAh, sAl, sBh, sBl, acc);
    int lane = threadIdx.x & 63, wid = threadIdx.x >> 6;
    int wr = wid >> 1, wc = wid & 1, l15 = lane & 15, l4 = lane >> 4;
#pragma unroll
    for (int fc = 0; fc < 4; ++fc) {
        int c = c0 + wc * 64 + fc * 16 + l15;
        float vv = v[b * 512 + c];
#pragma unroll
        for (int fr = 0; fr < 4; ++fr) {
            int row = m0 + wr * 64 + fr * 16 + (l4 << 2);
#pragma unroll
            for (int j = 0; j < 4; ++j)
                out[(size_t)(row + j) * 512 + c] = acc[fr][fc][j] + vv;
        }
    }
}

// ---------------------------------------------------------------------------
extern "C" void kernel_launch(void* const* d_in, const int* in_sizes, int n_in,
                              void* d_out, int out_size, void* d_ws, size_t ws_size,
                              hipStream_t stream) {
    (void)in_sizes; (void)n_in; (void)out_size;
    const float* x  = (const float*)d_in[0];
    const float* W1 = (const float*)d_in[1];
    const float* b1 = (const float*)d_in[2];
    const float* W2 = (const float*)d_in[3];
    const float* b2 = (const float*)d_in[4];
    const float* WR = (const float*)d_in[5];
    const float* bR = (const float*)d_in[6];
    float* out = (float*)d_out;

    // Workspace map (85.0 MB total). u sits right after C so one memset
    // zeroes both.
    char* w = (char*)d_ws;
    short* xth  = (short*)(w);                    // 33,554,432 B
    short* xtl  = (short*)(w + 33554432);         // 33,554,432 B
    char*  buf1 = w + 67108864;                   //  8,388,608 B: C, then G-pair
    float* C    = (float*)buf1;
    short* Gth  = (short*)buf1;
    short* Gtl  = (short*)(buf1 + 4194304);
    float* u    = (float*)(w + 75497472);         //     16,384 B
    char*  buf2 = w + 75513856;                   //  8,388,608 B: T, then H-pair
    float* T    = (float*)buf2;
    short* Hth  = (short*)buf2;
    short* Htl  = (short*)(buf2 + 4194304);
    short* W1th = (short*)(w + 83902464);         //    524,288 B
    short* W1tl = (short*)(w + 84426752);         //    524,288 B
    float* p2   = (float*)(w + 84951040);         //     16,384 B each
    float* y    = (float*)(w + 84967424);
    float* v    = (float*)(w + 84983808);         // ends 85,000,192
    if (ws_size < 85000192) return;               // clean fail, no corruption

    (void)hipMemsetAsync(C, 0, 8388608 + 16384, stream);  // C and u
    hipLaunchKernelGGL(splitx_w1t_kernel, dim3(4160), dim3(256), 0, stream,
                       x, xth, xtl, u, W1, W1th, W1tl);
    hipLaunchKernelGGL(xtx_vecs_kernel, dim3(576), dim3(256), 0, stream,
                       xth, xtl, C, W2, WR, u, p2, y);
    hipLaunchKernelGGL(s1_kernel, dim3(128), dim3(256), 0, stream, W2, C, T);
    hipLaunchKernelGGL(s2_kernel, dim3(128), dim3(256), 0, stream,
                       T, WR, bR, b2, p2, y, Gth, Gtl);
    hipLaunchKernelGGL(s3_v2_kernel, dim3(136), dim3(256), 0, stream,
                       W1th, W1tl, Gth, Gtl, Hth, Htl, b1, v);
    hipLaunchKernelGGL(d_kernel, dim3(1024), dim3(256), 0, stream,
                       x, Hth, Htl, v, out);
}